// Round 10
// baseline (309.280 us; speedup 1.0000x reference)
//
#include <hip/hip_runtime.h>
#include <math.h>

#define B_ 4
#define C_ 256
#define CI_ 128
#define N_ 4096
#define QT_ 128
#define KT_ 64
#define KH_ 2048
#define NITER (KH_ / KT_)     // 32
#define KSTRIDE 264   // 256 + 8 pad (verified round 3)
#define VSTRIDE 72    // 64 + 8 pad (verified round 3)
constexpr float EPS_ = 1e-5f;

typedef __attribute__((ext_vector_type(8))) short bfrag;
typedef __attribute__((ext_vector_type(4))) float f4;

__device__ __forceinline__ unsigned short bf16r(float x) {
    unsigned u = __float_as_uint(x);
    u += 0x7FFFu + ((u >> 16) & 1u);
    return (unsigned short)(u >> 16);
}
__device__ __forceinline__ unsigned pack_bf16(float a, float b) {
    unsigned ua = __float_as_uint(a); ua += 0x7FFFu + ((ua >> 16) & 1u);
    unsigned ub = __float_as_uint(b); ub += 0x7FFFu + ((ub >> 16) & 1u);
    return (ua >> 16) | (ub & 0xFFFF0000u);
}

// ---------------- K1: x -> xt bf16 [b][n][c]; block(0,0,0) zeroes sums ---
__global__ __launch_bounds__(256) void make_xt(const float* __restrict__ x,
                                               unsigned short* __restrict__ xt,
                                               float* __restrict__ sums) {
    if (blockIdx.x == 0 && blockIdx.y == 0 && blockIdx.z == 0) {
        sums[threadIdx.x] = 0.f;
        sums[threadIdx.x + 256] = 0.f;
    }
    int n  = blockIdx.x * 256 + threadIdx.x;
    int c0 = blockIdx.y * 8;
    int b  = blockIdx.z;
    const float* xb = x + (size_t)b * C_ * N_;
    unsigned short buf[8];
#pragma unroll
    for (int c = 0; c < 8; c++) buf[c] = bf16r(xb[(c0 + c) * N_ + n]);   // coalesced
    uint4 v;
    v.x = buf[0] | ((unsigned)buf[1] << 16);
    v.y = buf[2] | ((unsigned)buf[3] << 16);
    v.z = buf[4] | ((unsigned)buf[5] << 16);
    v.w = buf[6] | ((unsigned)buf[7] << 16);
    *(uint4*)&xt[((size_t)b * N_ + n) * C_ + c0] = v;
}

// ---------------- K2: g conv, k-chunked x8 -> s_load_dwordx8 weights -----
__global__ __launch_bounds__(256) void gconv(const float* __restrict__ x,
                                             const float* __restrict__ gw,
                                             const float* __restrict__ gb,
                                             unsigned short* __restrict__ gx) {
    int m  = blockIdx.x * 256 + threadIdx.x;
    int o0 = blockIdx.y * 16;
    int b  = blockIdx.z;
    const float* xb = x + (size_t)b * C_ * N_;
    float acc[16];
#pragma unroll
    for (int o = 0; o < 16; o++) acc[o] = gb[o0 + o];
    for (int c0 = 0; c0 < C_; c0 += 8) {
        float xv[8];
#pragma unroll
        for (int j = 0; j < 8; j++) xv[j] = xb[(c0 + j) * N_ + m];   // 8 indep coalesced
#pragma unroll
        for (int o = 0; o < 16; o++) {
            const float* wr = gw + (size_t)(o0 + o) * C_ + c0;       // uniform, 8 contig
#pragma unroll
            for (int j = 0; j < 8; j++) acc[o] += wr[j] * xv[j];     // ascending-c order
        }
    }
#pragma unroll
    for (int o = 0; o < 16; o++)
        gx[((size_t)b * CI_ + o0 + o) * N_ + m] = bf16r(acc[o]);     // coalesced
}

// ---------------- K3: MFMA flash attention — VERBATIM round 9 ------------
__global__ __launch_bounds__(512, 1) void attn(const unsigned short* __restrict__ xt,
                                               const unsigned short* __restrict__ gx,
                                               float* __restrict__ Yp,
                                               float* __restrict__ ml) {
    __shared__ __align__(16) unsigned short Ks[2][64 * KSTRIDE];    // 2 x 33 KB
    __shared__ __align__(16) unsigned short Vs[2][128 * VSTRIDE];   // 2 x 18 KB
    __shared__ __align__(16) unsigned short Ps[128 * VSTRIDE];      // 18 KB

    const int tid  = threadIdx.x;
    const int lane = tid & 63, w = tid >> 6;     // w in 0..7
    const int quad = lane >> 4, ql = lane & 15;
    const int half = blockIdx.x & 1;
    const int b    = (blockIdx.x & 7) >> 1;      // (half,b) constant per XCD residue
    const int qt   = blockIdx.x >> 3;
    const int n0   = qt * QT_;
    const int kbase = half * KH_;
    const unsigned short* xtb = xt + (size_t)b * N_ * C_;
    const unsigned short* gxb = gx + (size_t)b * CI_ * N_;

    bfrag qb[8];
#pragma unroll
    for (int ks = 0; ks < 8; ks++)
        qb[ks] = *(const bfrag*)(xtb + (size_t)(n0 + 16 * w + ql) * C_ + 32 * ks + quad * 8);

    f4 yacc[8];
    const f4 zero4 = {0.f, 0.f, 0.f, 0.f};
#pragma unroll
    for (int i = 0; i < 8; i++) yacc[i] = zero4;
    float mrun = -INFINITY, lrun = 0.f;

    uint4 kreg[4], vreg[2];
#pragma unroll
    for (int r = 0; r < 4; r++) {
        int idx = r * 512 + tid;
        kreg[r] = *(const uint4*)(xtb + (size_t)(kbase + (idx >> 5)) * C_ + (idx & 31) * 8);
    }
#pragma unroll
    for (int r = 0; r < 2; r++) {
        int idx = r * 512 + tid;
        vreg[r] = *(const uint4*)(gxb + (size_t)(idx >> 3) * N_ + kbase + (idx & 7) * 8);
    }
#pragma unroll
    for (int r = 0; r < 4; r++) {
        int idx = r * 512 + tid;
        *(uint4*)&Ks[0][(idx >> 5) * KSTRIDE + (idx & 31) * 8] = kreg[r];
    }
#pragma unroll
    for (int r = 0; r < 2; r++) {
        int idx = r * 512 + tid;
        *(uint4*)&Vs[0][(idx >> 3) * VSTRIDE + (idx & 7) * 8] = vreg[r];
    }
#pragma unroll
    for (int r = 0; r < 4; r++) {
        int idx = r * 512 + tid;
        kreg[r] = *(const uint4*)(xtb + (size_t)(kbase + KT_ + (idx >> 5)) * C_ + (idx & 31) * 8);
    }
#pragma unroll
    for (int r = 0; r < 2; r++) {
        int idx = r * 512 + tid;
        vreg[r] = *(const uint4*)(gxb + (size_t)(idx >> 3) * N_ + kbase + KT_ + (idx & 7) * 8);
    }
    __syncthreads();                             // buf0 ready

    for (int it = 0; it < NITER; ++it) {
        const int cur = it & 1, nxt = cur ^ 1;

        if (it + 1 < NITER) {
#pragma unroll
            for (int r = 0; r < 4; r++) {
                int idx = r * 512 + tid;
                *(uint4*)&Ks[nxt][(idx >> 5) * KSTRIDE + (idx & 31) * 8] = kreg[r];
            }
#pragma unroll
            for (int r = 0; r < 2; r++) {
                int idx = r * 512 + tid;
                *(uint4*)&Vs[nxt][(idx >> 3) * VSTRIDE + (idx & 7) * 8] = vreg[r];
            }
        }
        if (it + 2 < NITER) {
            const int t0 = kbase + (it + 2) * KT_;
#pragma unroll
            for (int r = 0; r < 4; r++) {
                int idx = r * 512 + tid;
                kreg[r] = *(const uint4*)(xtb + (size_t)(t0 + (idx >> 5)) * C_ + (idx & 31) * 8);
            }
#pragma unroll
            for (int r = 0; r < 2; r++) {
                int idx = r * 512 + tid;
                vreg[r] = *(const uint4*)(gxb + (size_t)(idx >> 3) * N_ + t0 + (idx & 7) * 8);
            }
        }

        // ---- St = K.Q : 32 mfma / wave ----
        f4 sacc[4];
#pragma unroll
        for (int i = 0; i < 4; i++) sacc[i] = zero4;
#pragma unroll
        for (int ks = 0; ks < 8; ks++) {
            bfrag ka[4];
#pragma unroll
            for (int i = 0; i < 4; i++)
                ka[i] = *(const bfrag*)&Ks[cur][(16 * i + ql) * KSTRIDE + 32 * ks + quad * 8];
#pragma unroll
            for (int i = 0; i < 4; i++)
                sacc[i] = __builtin_amdgcn_mfma_f32_16x16x32_bf16(ka[i], qb[ks], sacc[i], 0, 0, 0);
        }

        // ---- online softmax over m ----
        float mx = -INFINITY;
#pragma unroll
        for (int i = 0; i < 4; i++)
#pragma unroll
            for (int r = 0; r < 4; r++) mx = fmaxf(mx, sacc[i][r]);
        mx = fmaxf(mx, __shfl_xor(mx, 16, 64));
        mx = fmaxf(mx, __shfl_xor(mx, 32, 64));
        float mn = fmaxf(mrun, mx);
        float alpha = __expf(mrun - mn);       // -inf -> 0 first iter
        mrun = mn;
        lrun *= alpha;
        if (__any(alpha != 1.f)) {
#pragma unroll
            for (int i = 0; i < 8; i++) {
                yacc[i][0] *= alpha; yacc[i][1] *= alpha;
                yacc[i][2] *= alpha; yacc[i][3] *= alpha;
            }
        }

        // ---- P = exp(S-m) -> Ps[q][m] (one aligned b64 per i) ----
        {
            int q = 16 * w + ql;
            float lsum = 0.f;
#pragma unroll
            for (int i = 0; i < 4; i++) {
                float p0 = __expf(sacc[i][0] - mrun);
                float p1 = __expf(sacc[i][1] - mrun);
                float p2 = __expf(sacc[i][2] - mrun);
                float p3 = __expf(sacc[i][3] - mrun);
                lsum += (p0 + p1) + (p2 + p3);
                int idx = q * VSTRIDE + 16 * i + 4 * quad;   // m = 16i+4quad+r
                unsigned long long pv = (unsigned long long)pack_bf16(p0, p1)
                                      | ((unsigned long long)pack_bf16(p2, p3) << 32);
                *(unsigned long long*)&Ps[idx] = pv;         // 8B-aligned b64
            }
            lrun += lsum;
        }

        // ---- Yt += Vt.P : 16 mfma / wave ----
#pragma unroll
        for (int ks = 0; ks < 2; ks++) {
            bfrag pb, va[8];
            pb = *(const bfrag*)&Ps[(16 * w + ql) * VSTRIDE + 32 * ks + quad * 8];
#pragma unroll
            for (int i = 0; i < 8; i++)
                va[i] = *(const bfrag*)&Vs[cur][(16 * i + ql) * VSTRIDE + 32 * ks + quad * 8];
#pragma unroll
            for (int i = 0; i < 8; i++)
                yacc[i] = __builtin_amdgcn_mfma_f32_16x16x32_bf16(va[i], pb, yacc[i], 0, 0, 0);
        }

        __syncthreads();   // buf[nxt] writes done; buf[cur] reads done
    }

    // ---- epilogue ----
    lrun += __shfl_xor(lrun, 16, 64);
    lrun += __shfl_xor(lrun, 32, 64);
    {
        int n = n0 + 16 * w + ql;
#pragma unroll
        for (int i = 0; i < 8; i++)
#pragma unroll
            for (int r = 0; r < 4; r++) {
                int ci = 16 * i + quad * 4 + r;
                Yp[(((size_t)half * 4 + b) * CI_ + ci) * N_ + n] = yacc[i][r];
            }
        if (quad == 0) {
            ml[(((size_t)half * 4 + b) * N_ + n) * 2]     = mrun;
            ml[(((size_t)half * 4 + b) * N_ + n) * 2 + 1] = lrun;
        }
    }
}

// ---------------- K4: merge split-K halves -> y fp32 (float4) ------------
__global__ __launch_bounds__(256) void merge(const float* __restrict__ Yp,
                                             const float* __restrict__ ml,
                                             float* __restrict__ y) {
    int n4 = blockIdx.x * 256 + threadIdx.x;     // float4 index over N/4
    int ci = blockIdx.y;
    int b  = blockIdx.z;
    int n  = n4 * 4;
    float4 a0 = *(const float4*)&ml[((size_t)b * N_ + n) * 2];
    float4 a1 = *(const float4*)&ml[((size_t)b * N_ + n + 2) * 2];
    float4 c0 = *(const float4*)&ml[(((size_t)4 + b) * N_ + n) * 2];
    float4 c1 = *(const float4*)&ml[(((size_t)4 + b) * N_ + n + 2) * 2];
    float m0[4] = {a0.x, a0.z, a1.x, a1.z};
    float l0[4] = {a0.y, a0.w, a1.y, a1.w};
    float m1[4] = {c0.x, c0.z, c1.x, c1.z};
    float l1[4] = {c0.y, c0.w, c1.y, c1.w};
    float w0[4], w1[4];
#pragma unroll
    for (int k = 0; k < 4; k++) {
        float mm = fmaxf(m0[k], m1[k]);
        float e0 = __expf(m0[k] - mm), e1 = __expf(m1[k] - mm);
        float inv = 1.f / (e0 * l0[k] + e1 * l1[k]);
        w0[k] = e0 * inv;
        w1[k] = e1 * inv;
    }
    size_t base = ((size_t)b * CI_ + ci) * N_ + n;
    float4 y0 = *(const float4*)&Yp[base];
    float4 y1 = *(const float4*)&Yp[(size_t)4 * CI_ * N_ + base];
    float4 o;
    o.x = w0[0] * y0.x + w1[0] * y1.x;
    o.y = w0[1] * y0.y + w1[1] * y1.y;
    o.z = w0[2] * y0.z + w1[2] * y1.z;
    o.w = w0[3] * y0.w + w1[3] * y1.w;
    *(float4*)&y[base] = o;
}

// ---------------- K5: W conv + BN stats, k-chunked x8 weights ------------
__global__ __launch_bounds__(256) void wconv_stats(const float* __restrict__ y,
                                                   const float* __restrict__ Ww,
                                                   const float* __restrict__ Wb,
                                                   float* __restrict__ wy,
                                                   float* __restrict__ sums) {
    int n   = blockIdx.x * 256 + threadIdx.x;
    int co0 = blockIdx.y * 16;
    int b   = blockIdx.z;
    const float* yb = y + (size_t)b * CI_ * N_;
    float acc[16];
#pragma unroll
    for (int o = 0; o < 16; o++) acc[o] = Wb[co0 + o];
    for (int c0 = 0; c0 < CI_; c0 += 8) {
        float yv[8];
#pragma unroll
        for (int j = 0; j < 8; j++) yv[j] = yb[(c0 + j) * N_ + n];   // 8 indep coalesced
#pragma unroll
        for (int o = 0; o < 16; o++) {
            const float* wr = Ww + (size_t)(co0 + o) * CI_ + c0;     // uniform, 8 contig
#pragma unroll
            for (int j = 0; j < 8; j++) acc[o] += wr[j] * yv[j];     // ascending-ci order
        }
    }
    float* wyb = wy + (size_t)b * C_ * N_;
#pragma unroll
    for (int o = 0; o < 16; o++) wyb[(co0 + o) * N_ + n] = acc[o];   // coalesced

    __shared__ float wred[32][4];
    int lane = threadIdx.x & 63, wid = threadIdx.x >> 6;
#pragma unroll
    for (int o = 0; o < 16; o++) {
        float s1 = acc[o], s2 = acc[o] * acc[o];
#pragma unroll
        for (int off = 32; off > 0; off >>= 1) {
            s1 += __shfl_down(s1, off, 64);
            s2 += __shfl_down(s2, off, 64);
        }
        if (lane == 0) { wred[o][wid] = s1; wred[16 + o][wid] = s2; }
    }
    __syncthreads();
    if (threadIdx.x < 32) {
        int q = threadIdx.x;
        float t = wred[q][0] + wred[q][1] + wred[q][2] + wred[q][3];
        int o = q & 15;
        if (q < 16) atomicAdd(&sums[co0 + o], t);
        else        atomicAdd(&sums[256 + co0 + o], t);
    }
}

// ---------------- K6: BN finalize + residual (float4, wy aliased to out) -
__global__ __launch_bounds__(256) void bn_finalize(float* __restrict__ wy,
                                                   const float* __restrict__ x,
                                                   const float* __restrict__ sums,
                                                   const float* __restrict__ gamma,
                                                   const float* __restrict__ beta,
                                                   float* __restrict__ out) {
    int n4 = blockIdx.x * 256 + threadIdx.x;     // float4 index, N/4 per (co,b)
    int co = blockIdx.y;
    int b  = blockIdx.z;
    float cnt  = (float)(B_ * N_);
    float mean = sums[co] / cnt;
    float var  = sums[256 + co] / cnt - mean * mean;
    float sc   = rsqrtf(var + EPS_) * gamma[co];
    float bt   = beta[co];
    size_t idx = ((size_t)b * C_ + co) * N_ + (size_t)n4 * 4;
    float4 wv = *(const float4*)&wy[idx];
    float4 xv = *(const float4*)&x[idx];
    float4 o;
    o.x = (wv.x - mean) * sc + bt + xv.x;
    o.y = (wv.y - mean) * sc + bt + xv.y;
    o.z = (wv.z - mean) * sc + bt + xv.z;
    o.w = (wv.w - mean) * sc + bt + xv.w;
    *(float4*)&out[idx] = o;
}

extern "C" void kernel_launch(void* const* d_in, const int* in_sizes, int n_in,
                              void* d_out, int out_size, void* d_ws, size_t ws_size,
                              hipStream_t stream) {
    const float* x     = (const float*)d_in[0];
    const float* gw    = (const float*)d_in[1];
    const float* gb    = (const float*)d_in[2];
    const float* Ww    = (const float*)d_in[3];
    const float* Wb    = (const float*)d_in[4];
    const float* gamma = (const float*)d_in[5];
    const float* beta  = (const float*)d_in[6];
    float* out = (float*)d_out;
    float* ws  = (float*)d_ws;

    // ws (floats): total 7,406,080 = 29.6 MB (round-3 proven footprint)
    unsigned short* xt  = (unsigned short*)ws;              // 8 MB  [0, 2,097,152)
    unsigned short* gxb = (unsigned short*)(ws + 2097152);  // 4 MB  [2,097,152, 3,145,728)
    float* Yp   = ws + 3145728;                             // 16 MB [3,145,728, 7,340,032)
    float* ml   = ws + 7340032;                             // 256 KB
    float* sums = ws + 7405568;                             // 2 KB
    float* y    = ws;                                       // aliases xt (dead after attn)
    float* wy   = out;                                      // wy aliased onto d_out

    hipLaunchKernelGGL(make_xt, dim3(16, 32, 4), dim3(256), 0, stream, x, xt, sums);
    hipLaunchKernelGGL(gconv, dim3(16, 8, 4), dim3(256), 0, stream, x, gw, gb, gxb);
    hipLaunchKernelGGL(attn, dim3(256), dim3(512), 0, stream, xt, gxb, Yp, ml);
    hipLaunchKernelGGL(merge, dim3(4, 128, 4), dim3(256), 0, stream, Yp, ml, y);
    hipLaunchKernelGGL(wconv_stats, dim3(16, 16, 4), dim3(256), 0, stream, y, Ww, Wb, wy, sums);
    hipLaunchKernelGGL(bn_finalize, dim3(4, 256, 4), dim3(256), 0, stream, wy, x, sums, gamma, beta, out);
}

// Round 11
// 295.563 us; speedup vs baseline: 1.0464x; 1.0464x over previous
//
#include <hip/hip_runtime.h>
#include <math.h>

#define B_ 4
#define C_ 256
#define CI_ 128
#define N_ 4096
#define QT_ 128
#define KT_ 64
#define KH_ 2048
#define NITER (KH_ / KT_)     // 32
#define KSTRIDE 264   // 256 + 8 pad (verified round 3)
#define VSTRIDE 72    // 64 + 8 pad (verified round 3)
constexpr float EPS_ = 1e-5f;

typedef __attribute__((ext_vector_type(8))) short bfrag;
typedef __attribute__((ext_vector_type(4))) float f4;

__device__ __forceinline__ unsigned short bf16r(float x) {
    unsigned u = __float_as_uint(x);
    u += 0x7FFFu + ((u >> 16) & 1u);
    return (unsigned short)(u >> 16);
}
__device__ __forceinline__ unsigned pack_bf16(float a, float b) {
    unsigned ua = __float_as_uint(a); ua += 0x7FFFu + ((ua >> 16) & 1u);
    unsigned ub = __float_as_uint(b); ub += 0x7FFFu + ((ub >> 16) & 1u);
    return (ua >> 16) | (ub & 0xFFFF0000u);
}

// ---------------- K1: x -> xt bf16 [b][n][c]; block(0,0,0) zeroes sums ---
__global__ __launch_bounds__(256) void make_xt(const float* __restrict__ x,
                                               unsigned short* __restrict__ xt,
                                               float* __restrict__ sums) {
    if (blockIdx.x == 0 && blockIdx.y == 0 && blockIdx.z == 0) {
        sums[threadIdx.x] = 0.f;
        sums[threadIdx.x + 256] = 0.f;
    }
    int n  = blockIdx.x * 256 + threadIdx.x;
    int c0 = blockIdx.y * 8;
    int b  = blockIdx.z;
    const float* xb = x + (size_t)b * C_ * N_;
    unsigned short buf[8];
#pragma unroll
    for (int c = 0; c < 8; c++) buf[c] = bf16r(xb[(c0 + c) * N_ + n]);   // coalesced
    uint4 v;
    v.x = buf[0] | ((unsigned)buf[1] << 16);
    v.y = buf[2] | ((unsigned)buf[3] << 16);
    v.z = buf[4] | ((unsigned)buf[5] << 16);
    v.w = buf[6] | ((unsigned)buf[7] << 16);
    *(uint4*)&xt[((size_t)b * N_ + n) * C_ + c0] = v;
}

// ---------------- K2: g conv (verbatim round 10) -------------------------
__global__ __launch_bounds__(256) void gconv(const float* __restrict__ x,
                                             const float* __restrict__ gw,
                                             const float* __restrict__ gb,
                                             unsigned short* __restrict__ gx) {
    int m  = blockIdx.x * 256 + threadIdx.x;
    int o0 = blockIdx.y * 16;
    int b  = blockIdx.z;
    const float* xb = x + (size_t)b * C_ * N_;
    float acc[16];
#pragma unroll
    for (int o = 0; o < 16; o++) acc[o] = gb[o0 + o];
    for (int c0 = 0; c0 < C_; c0 += 8) {
        float xv[8];
#pragma unroll
        for (int j = 0; j < 8; j++) xv[j] = xb[(c0 + j) * N_ + m];
#pragma unroll
        for (int o = 0; o < 16; o++) {
            const float* wr = gw + (size_t)(o0 + o) * C_ + c0;
#pragma unroll
            for (int j = 0; j < 8; j++) acc[o] += wr[j] * xv[j];
        }
    }
#pragma unroll
    for (int o = 0; o < 16; o++)
        gx[((size_t)b * CI_ + o0 + o) * N_ + m] = bf16r(acc[o]);
}

// ---------------- K3: MFMA flash attention — 1024 thr, m-split groups ----
// grid 256; 16 waves = 4/SIMD. Group g = w>>3 owns m-half [32g,32g+32) of
// each K-tile with its own online softmax; epilogue merges groups via LDS
// (verified split-K merge algebra). Double-buffered Ks/Vs, 1 barrier/iter.
__global__ __launch_bounds__(1024, 4) void attn(const unsigned short* __restrict__ xt,
                                                const unsigned short* __restrict__ gx,
                                                float* __restrict__ Yp,
                                                float* __restrict__ ml) {
    __shared__ __align__(16) unsigned short Ks[2][64 * KSTRIDE];    // 2 x 33 KB
    __shared__ __align__(16) unsigned short Vs[2][128 * VSTRIDE];   // 2 x 18 KB
    __shared__ __align__(16) unsigned short Ps[128 * VSTRIDE];      // 18 KB

    const int tid  = threadIdx.x;
    const int lane = tid & 63, w = tid >> 6;     // w in 0..15
    const int wq = w & 7, g = w >> 3;            // q-band, m-group
    const int quad = lane >> 4, ql = lane & 15;
    const int half = blockIdx.x & 1;
    const int b    = (blockIdx.x & 7) >> 1;
    const int qt   = blockIdx.x >> 3;
    const int n0   = qt * QT_;
    const int kbase = half * KH_;
    const unsigned short* xtb = xt + (size_t)b * N_ * C_;
    const unsigned short* gxb = gx + (size_t)b * CI_ * N_;

    // Q B-frags: q rows n0 + 16*wq + ql (both groups load the same rows)
    bfrag qb[8];
#pragma unroll
    for (int ks = 0; ks < 8; ks++)
        qb[ks] = *(const bfrag*)(xtb + (size_t)(n0 + 16 * wq + ql) * C_ + 32 * ks + quad * 8);

    f4 yacc[8];
    const f4 zero4 = {0.f, 0.f, 0.f, 0.f};
#pragma unroll
    for (int i = 0; i < 8; i++) yacc[i] = zero4;
    float mrun = -INFINITY, lrun = 0.f;

    // prologue: tile0 -> regs -> buf0; tile1 -> regs
    uint4 kreg[2], vreg[1];
#pragma unroll
    for (int r = 0; r < 2; r++) {
        int idx = r * 1024 + tid;
        kreg[r] = *(const uint4*)(xtb + (size_t)(kbase + (idx >> 5)) * C_ + (idx & 31) * 8);
    }
    vreg[0] = *(const uint4*)(gxb + (size_t)(tid >> 3) * N_ + kbase + (tid & 7) * 8);
#pragma unroll
    for (int r = 0; r < 2; r++) {
        int idx = r * 1024 + tid;
        *(uint4*)&Ks[0][(idx >> 5) * KSTRIDE + (idx & 31) * 8] = kreg[r];
    }
    *(uint4*)&Vs[0][(tid >> 3) * VSTRIDE + (tid & 7) * 8] = vreg[0];
#pragma unroll
    for (int r = 0; r < 2; r++) {
        int idx = r * 1024 + tid;
        kreg[r] = *(const uint4*)(xtb + (size_t)(kbase + KT_ + (idx >> 5)) * C_ + (idx & 31) * 8);
    }
    vreg[0] = *(const uint4*)(gxb + (size_t)(tid >> 3) * N_ + kbase + KT_ + (tid & 7) * 8);
    __syncthreads();                             // buf0 ready

    for (int it = 0; it < NITER; ++it) {
        const int cur = it & 1, nxt = cur ^ 1;

        if (it + 1 < NITER) {
#pragma unroll
            for (int r = 0; r < 2; r++) {
                int idx = r * 1024 + tid;
                *(uint4*)&Ks[nxt][(idx >> 5) * KSTRIDE + (idx & 31) * 8] = kreg[r];
            }
            *(uint4*)&Vs[nxt][(tid >> 3) * VSTRIDE + (tid & 7) * 8] = vreg[0];
        }
        if (it + 2 < NITER) {
            const int t0 = kbase + (it + 2) * KT_;
#pragma unroll
            for (int r = 0; r < 2; r++) {
                int idx = r * 1024 + tid;
                kreg[r] = *(const uint4*)(xtb + (size_t)(t0 + (idx >> 5)) * C_ + (idx & 31) * 8);
            }
            vreg[0] = *(const uint4*)(gxb + (size_t)(tid >> 3) * N_ + t0 + (tid & 7) * 8);
        }

        // ---- St = K.Q on this group's m-half : 16 mfma / wave ----
        f4 sacc[2];
        sacc[0] = zero4; sacc[1] = zero4;
#pragma unroll
        for (int ks = 0; ks < 8; ks++) {
            bfrag ka[2];
#pragma unroll
            for (int i = 0; i < 2; i++)
                ka[i] = *(const bfrag*)&Ks[cur][(32 * g + 16 * i + ql) * KSTRIDE + 32 * ks + quad * 8];
#pragma unroll
            for (int i = 0; i < 2; i++)
                sacc[i] = __builtin_amdgcn_mfma_f32_16x16x32_bf16(ka[i], qb[ks], sacc[i], 0, 0, 0);
        }

        // ---- group-local online softmax ----
        float mx = -INFINITY;
#pragma unroll
        for (int i = 0; i < 2; i++)
#pragma unroll
            for (int r = 0; r < 4; r++) mx = fmaxf(mx, sacc[i][r]);
        mx = fmaxf(mx, __shfl_xor(mx, 16, 64));
        mx = fmaxf(mx, __shfl_xor(mx, 32, 64));
        float mn = fmaxf(mrun, mx);
        float alpha = __expf(mrun - mn);       // -inf -> 0 first iter
        mrun = mn;
        lrun *= alpha;
        if (__any(alpha != 1.f)) {
#pragma unroll
            for (int i = 0; i < 8; i++) {
                yacc[i][0] *= alpha; yacc[i][1] *= alpha;
                yacc[i][2] *= alpha; yacc[i][3] *= alpha;
            }
        }

        // ---- P = exp(S-m) -> Ps[q][m], m in group's half (wave-private) ----
        {
            int q = 16 * wq + ql;
            float lsum = 0.f;
#pragma unroll
            for (int i = 0; i < 2; i++) {
                float p0 = __expf(sacc[i][0] - mrun);
                float p1 = __expf(sacc[i][1] - mrun);
                float p2 = __expf(sacc[i][2] - mrun);
                float p3 = __expf(sacc[i][3] - mrun);
                lsum += (p0 + p1) + (p2 + p3);
                int idx = q * VSTRIDE + 32 * g + 16 * i + 4 * quad;  // m = 32g+16i+4quad+r
                unsigned long long pv = (unsigned long long)pack_bf16(p0, p1)
                                      | ((unsigned long long)pack_bf16(p2, p3) << 32);
                *(unsigned long long*)&Ps[idx] = pv;
            }
            lrun += lsum;
        }

        // ---- Yt += Vt.P over group's m-half : 8 mfma / wave ----
        {
            bfrag pb, va[8];
            pb = *(const bfrag*)&Ps[(16 * wq + ql) * VSTRIDE + 32 * g + quad * 8];
#pragma unroll
            for (int i = 0; i < 8; i++)
                va[i] = *(const bfrag*)&Vs[cur][(16 * i + ql) * VSTRIDE + 32 * g + quad * 8];
#pragma unroll
            for (int i = 0; i < 8; i++)
                yacc[i] = __builtin_amdgcn_mfma_f32_16x16x32_bf16(va[i], pb, yacc[i], 0, 0, 0);
        }

        __syncthreads();   // buf[nxt] staged; buf[cur] + Ps reads done
    }

    // ---- epilogue: merge the two m-groups (split-K algebra), store ----
    lrun += __shfl_xor(lrun, 16, 64);
    lrun += __shfl_xor(lrun, 32, 64);

    float* PsF = (float*)Ps;          // Ps dead; 18432 B = 16 KB Ysc + 2 KB mlb
    float* Ysc = PsF;                 // [32 ci'][128 q]
    float* mlb = PsF + 4096;          // [2 g][128 q][2]

    const int q = 16 * wq + ql;
    if (quad == 0) {
        mlb[(g * 128 + q) * 2]     = mrun;
        mlb[(g * 128 + q) * 2 + 1] = lrun;
    }
    __syncthreads();
    float m0 = mlb[q * 2],           l0 = mlb[q * 2 + 1];
    float m1 = mlb[(128 + q) * 2],   l1 = mlb[(128 + q) * 2 + 1];
    float mm = fmaxf(m0, m1);
    float e0 = __expf(m0 - mm), e1 = __expf(m1 - mm);
    float lnew = e0 * l0 + e1 * l1;

#pragma unroll
    for (int c = 0; c < 4; c++) {                // ci chunks of 32
        if (g == 1) {
#pragma unroll
            for (int i2 = 0; i2 < 2; i2++) {
                int i = 2 * c + i2;
#pragma unroll
                for (int r = 0; r < 4; r++) {
                    int cip = 16 * i2 + 4 * quad + r;        // ci - 32c
                    Ysc[cip * 128 + q] = e1 * yacc[i][r];
                }
            }
        }
        __syncthreads();
        if (g == 0) {
#pragma unroll
            for (int i2 = 0; i2 < 2; i2++) {
                int i = 2 * c + i2;
#pragma unroll
                for (int r = 0; r < 4; r++) {
                    int ci = 16 * i + 4 * quad + r;
                    float v = e0 * yacc[i][r] + Ysc[(16 * i2 + 4 * quad + r) * 128 + q];
                    Yp[(((size_t)half * 4 + b) * CI_ + ci) * N_ + n0 + q] = v;
                }
            }
        }
        __syncthreads();
    }
    if (g == 0 && quad == 0) {
        ml[(((size_t)half * 4 + b) * N_ + n0 + q) * 2]     = mm;
        ml[(((size_t)half * 4 + b) * N_ + n0 + q) * 2 + 1] = lnew;
    }
}

// ---------------- K4: merge split-K halves -> y fp32 (float4) ------------
__global__ __launch_bounds__(256) void merge(const float* __restrict__ Yp,
                                             const float* __restrict__ ml,
                                             float* __restrict__ y) {
    int n4 = blockIdx.x * 256 + threadIdx.x;
    int ci = blockIdx.y;
    int b  = blockIdx.z;
    int n  = n4 * 4;
    float4 a0 = *(const float4*)&ml[((size_t)b * N_ + n) * 2];
    float4 a1 = *(const float4*)&ml[((size_t)b * N_ + n + 2) * 2];
    float4 c0 = *(const float4*)&ml[(((size_t)4 + b) * N_ + n) * 2];
    float4 c1 = *(const float4*)&ml[(((size_t)4 + b) * N_ + n + 2) * 2];
    float m0[4] = {a0.x, a0.z, a1.x, a1.z};
    float l0[4] = {a0.y, a0.w, a1.y, a1.w};
    float m1[4] = {c0.x, c0.z, c1.x, c1.z};
    float l1[4] = {c0.y, c0.w, c1.y, c1.w};
    float w0[4], w1[4];
#pragma unroll
    for (int k = 0; k < 4; k++) {
        float mm = fmaxf(m0[k], m1[k]);
        float e0 = __expf(m0[k] - mm), e1 = __expf(m1[k] - mm);
        float inv = 1.f / (e0 * l0[k] + e1 * l1[k]);
        w0[k] = e0 * inv;
        w1[k] = e1 * inv;
    }
    size_t base = ((size_t)b * CI_ + ci) * N_ + n;
    float4 y0 = *(const float4*)&Yp[base];
    float4 y1 = *(const float4*)&Yp[(size_t)4 * CI_ * N_ + base];
    float4 o;
    o.x = w0[0] * y0.x + w1[0] * y1.x;
    o.y = w0[1] * y0.y + w1[1] * y1.y;
    o.z = w0[2] * y0.z + w1[2] * y1.z;
    o.w = w0[3] * y0.w + w1[3] * y1.w;
    *(float4*)&y[base] = o;
}

// ---------------- K5: W conv + BN stats (verbatim round 10) --------------
__global__ __launch_bounds__(256) void wconv_stats(const float* __restrict__ y,
                                                   const float* __restrict__ Ww,
                                                   const float* __restrict__ Wb,
                                                   float* __restrict__ wy,
                                                   float* __restrict__ sums) {
    int n   = blockIdx.x * 256 + threadIdx.x;
    int co0 = blockIdx.y * 16;
    int b   = blockIdx.z;
    const float* yb = y + (size_t)b * CI_ * N_;
    float acc[16];
#pragma unroll
    for (int o = 0; o < 16; o++) acc[o] = Wb[co0 + o];
    for (int c0 = 0; c0 < CI_; c0 += 8) {
        float yv[8];
#pragma unroll
        for (int j = 0; j < 8; j++) yv[j] = yb[(c0 + j) * N_ + n];
#pragma unroll
        for (int o = 0; o < 16; o++) {
            const float* wr = Ww + (size_t)(co0 + o) * CI_ + c0;
#pragma unroll
            for (int j = 0; j < 8; j++) acc[o] += wr[j] * yv[j];
        }
    }
    float* wyb = wy + (size_t)b * C_ * N_;
#pragma unroll
    for (int o = 0; o < 16; o++) wyb[(co0 + o) * N_ + n] = acc[o];

    __shared__ float wred[32][4];
    int lane = threadIdx.x & 63, wid = threadIdx.x >> 6;
#pragma unroll
    for (int o = 0; o < 16; o++) {
        float s1 = acc[o], s2 = acc[o] * acc[o];
#pragma unroll
        for (int off = 32; off > 0; off >>= 1) {
            s1 += __shfl_down(s1, off, 64);
            s2 += __shfl_down(s2, off, 64);
        }
        if (lane == 0) { wred[o][wid] = s1; wred[16 + o][wid] = s2; }
    }
    __syncthreads();
    if (threadIdx.x < 32) {
        int qq = threadIdx.x;
        float t = wred[qq][0] + wred[qq][1] + wred[qq][2] + wred[qq][3];
        int o = qq & 15;
        if (qq < 16) atomicAdd(&sums[co0 + o], t);
        else         atomicAdd(&sums[256 + co0 + o], t);
    }
}

// ---------------- K6: BN finalize + residual (verbatim round 10) ---------
__global__ __launch_bounds__(256) void bn_finalize(float* __restrict__ wy,
                                                   const float* __restrict__ x,
                                                   const float* __restrict__ sums,
                                                   const float* __restrict__ gamma,
                                                   const float* __restrict__ beta,
                                                   float* __restrict__ out) {
    int n4 = blockIdx.x * 256 + threadIdx.x;
    int co = blockIdx.y;
    int b  = blockIdx.z;
    float cnt  = (float)(B_ * N_);
    float mean = sums[co] / cnt;
    float var  = sums[256 + co] / cnt - mean * mean;
    float sc   = rsqrtf(var + EPS_) * gamma[co];
    float bt   = beta[co];
    size_t idx = ((size_t)b * C_ + co) * N_ + (size_t)n4 * 4;
    float4 wv = *(const float4*)&wy[idx];
    float4 xv = *(const float4*)&x[idx];
    float4 o;
    o.x = (wv.x - mean) * sc + bt + xv.x;
    o.y = (wv.y - mean) * sc + bt + xv.y;
    o.z = (wv.z - mean) * sc + bt + xv.z;
    o.w = (wv.w - mean) * sc + bt + xv.w;
    *(float4*)&out[idx] = o;
}

extern "C" void kernel_launch(void* const* d_in, const int* in_sizes, int n_in,
                              void* d_out, int out_size, void* d_ws, size_t ws_size,
                              hipStream_t stream) {
    const float* x     = (const float*)d_in[0];
    const float* gw    = (const float*)d_in[1];
    const float* gb    = (const float*)d_in[2];
    const float* Ww    = (const float*)d_in[3];
    const float* Wb    = (const float*)d_in[4];
    const float* gamma = (const float*)d_in[5];
    const float* beta  = (const float*)d_in[6];
    float* out = (float*)d_out;
    float* ws  = (float*)d_ws;

    // ws (floats): total 7,406,080 = 29.6 MB (round-3 proven footprint)
    unsigned short* xt  = (unsigned short*)ws;              // 8 MB
    unsigned short* gxb = (unsigned short*)(ws + 2097152);  // 4 MB
    float* Yp   = ws + 3145728;                             // 16 MB
    float* ml   = ws + 7340032;                             // 256 KB
    float* sums = ws + 7405568;                             // 2 KB
    float* y    = ws;                                       // aliases xt (dead after attn)
    float* wy   = out;                                      // aliased onto d_out

    hipLaunchKernelGGL(make_xt, dim3(16, 32, 4), dim3(256), 0, stream, x, xt, sums);
    hipLaunchKernelGGL(gconv, dim3(16, 8, 4), dim3(256), 0, stream, x, gw, gb, gxb);
    hipLaunchKernelGGL(attn, dim3(256), dim3(1024), 0, stream, xt, gxb, Yp, ml);
    hipLaunchKernelGGL(merge, dim3(4, 128, 4), dim3(256), 0, stream, Yp, ml, y);
    hipLaunchKernelGGL(wconv_stats, dim3(16, 16, 4), dim3(256), 0, stream, y, Ww, Wb, wy, sums);
    hipLaunchKernelGGL(bn_finalize, dim3(4, 256, 4), dim3(256), 0, stream, wy, x, sums, gamma, beta, out);
}